// Round 14
// baseline (451.394 us; speedup 1.0000x reference)
//
#include <hip/hip_runtime.h>
#include <cstdint>
#include <cstddef>

#define NN   10000
#define EE   40000
#define DIN_ 11
#define DD   64
#define LL   4
#define BB   512
#define MM   3
#define K1   128   // 2*D
#define DD2  4096  // D*D
#define NPB  16    // nodes per k_conv block
#define CSPL 4     // chunk-split across blocks (R14: quarter-split; R6 proved finer>coarser)
#define CPB  2     // chunks per block = NCH / CSPL
#define ESLOT 12   // register-accumulated edge slots per wave
#define ECREG (8 * ESLOT)  // 96 register-tracked edges per block
#define EHW (ECREG * 8)    // uints per staged hn1c chunk buffer

typedef unsigned short ushort_t;
typedef unsigned int   uint_t;

typedef __bf16 bf16x8_t __attribute__((ext_vector_type(8)));
typedef float  f32x4_t  __attribute__((ext_vector_type(4)));
union FragU { uint4 u; bf16x8_t b; };

__device__ __forceinline__ float bfu(ushort_t u) { return __uint_as_float(((uint_t)u) << 16); }
__device__ __forceinline__ float bflo(uint_t u) { return __uint_as_float(u << 16); }
__device__ __forceinline__ float bfhi(uint_t u) { return __uint_as_float(u & 0xffff0000u); }
__device__ __forceinline__ ushort_t f2bf(float f) {
  uint_t u = __float_as_uint(f);
  u = (u + 0x7fffu + ((u >> 16) & 1u)) >> 16;
  return (ushort_t)u;
}
__device__ __forceinline__ uint_t pack2(float lo, float hi) {
  return (uint_t)f2bf(lo) | ((uint_t)f2bf(hi) << 16);
}
__device__ __forceinline__ float sigmf_(float x) { return 1.f / (1.f + expf(-x)); }
__device__ __forceinline__ float siluf_(float x) { return x / (1.f + expf(-x)); }

#if defined(__HIP_DEVICE_COMPILE__) && __has_builtin(__builtin_amdgcn_fdot2_f32_bf16)
typedef __bf16 bf16x2_t __attribute__((ext_vector_type(2)));
__device__ __forceinline__ float dot2a(uint_t a, uint_t b, float c) {
  union { uint_t u; bf16x2_t v; } ua, ub;
  ua.u = a; ub.u = b;
  return __builtin_amdgcn_fdot2_f32_bf16(ua.v, ub.v, c, false);
}
#else
__device__ __forceinline__ float dot2a(uint_t a, uint_t b, float c) {
  return c + bflo(a) * bflo(b) + bfhi(a) * bfhi(b);
}
#endif

// ---------------- canonicalize float inputs to fp32 (self-detecting dtype) ----------------
#define NCANON 16
struct CanonArgs {
  const void* src[NCANON];
  float* dst[NCANON];
  int n[NCANON];
};
__global__ void k_canon(CanonArgs a, const ushort_t* __restrict__ ea, int* __restrict__ flag) {
  __shared__ int bad;
  if (threadIdx.x == 0) bad = 0;
  __syncthreads();
  ushort_t u = ea[threadIdx.x];
  if ((u & 0x8000u) || u > 0x3F80u) atomicAdd(&bad, 1);
  __syncthreads();
  const int isbf = (bad == 0) ? 1 : 0;
  if (blockIdx.x == 0 && blockIdx.y == 0 && threadIdx.x == 0) *flag = isbf;
  const int ai = blockIdx.y;
  const int n = a.n[ai];
  const int i = blockIdx.x * 256 + threadIdx.x;
  if (i >= n) return;
  float v;
  if (isbf) v = bfu(((const ushort_t*)a.src[ai])[i]);
  else      v = ((const float*)a.src[ai])[i];
  a.dst[ai][i] = v;
}

// ---------------- Wn2 repack into MFMA B-fragment order (coalesced) ----------------
__global__ void k_wn2m(const void* __restrict__ Wn2, uint_t* __restrict__ out,
                       const int* __restrict__ flag) {
  __shared__ ushort_t row[DD2];  // 8 KB
  const int k = blockIdx.x, tid = threadIdx.x;
  if (*flag) {
    const uint4* src = (const uint4*)((const ushort_t*)Wn2 + (size_t)k * DD2);
    ((uint4*)row)[tid] = src[tid];
    ((uint4*)row)[tid + 256] = src[tid + 256];
  } else {
    const float* src = (const float*)Wn2 + (size_t)k * DD2;
    for (int j = 0; j < 16; ++j) row[tid + 256 * j] = f2bf(src[tid + 256 * j]);
  }
  __syncthreads();
  const int kpg = k >> 1, par = k & 1;
  const int lane = tid >> 2, jp = tid & 3;
  const int q = lane >> 4, n = lane & 15;
  for (int fc = 0; fc < 4; ++fc) {
#pragma unroll
    for (int hf = 0; hf < 2; ++hf) {
      int d0 = hf * 32 + q * 8 + 2 * jp;
      int f = fc * 16 + n;
      uint_t lo = row[d0 * 64 + f], hi = row[(d0 + 1) * 64 + f];
      out[((((size_t)kpg * 4 + fc) * 2 + par) * 2 + hf) * 256 + tid] = lo | (hi << 16);
    }
  }
}

// ---------------- LSTM weight transpose: Wiht[i][j], Whht[i][j] ----------------
__global__ void k_wT(const float* __restrict__ Wihc, const float* __restrict__ Whhc,
                     float* __restrict__ Wiht, float* __restrict__ Whht) {
  int idx = blockIdx.x * 256 + threadIdx.x;
  if (idx < 4 * DD * K1) {
    int j = idx >> 7, i = idx & 127;  // Wihc[j][i]
    Wiht[i * 256 + j] = Wihc[idx];
  }
  if (idx < 4 * DD * DD) {
    int j = idx >> 6, i = idx & 63;   // Whhc[j][i]
    Whht[i * 256 + j] = Whhc[idx];
  }
}

// ---------------- node embed: 4 nodes/block; h, hpk, nbias ----------------
__global__ __launch_bounds__(256) void k_embed(
    const float* __restrict__ x, const float* __restrict__ W0,
    const float* __restrict__ b0, const float* __restrict__ bn2,
    float* __restrict__ h, uint_t* __restrict__ hpk,
    float* __restrict__ nbias) {
  __shared__ float xs[4][DIN_];
  __shared__ float hl[4][DD];
  const int tid = threadIdx.x, w = tid >> 6, f = tid & 63;
  const int n = blockIdx.x * 4 + w;
  if (f < DIN_) xs[w][f] = x[n * DIN_ + f];
  __syncthreads();
  float a = b0[f];
  for (int i = 0; i < DIN_; ++i) a += xs[w][i] * W0[i * DD + f];
  h[(size_t)n * DD + f] = a;
  hl[w][f] = a;
  float other = __shfl_down(a, 1);
  if ((f & 1) == 0)
    hpk[(size_t)n * 32 + (f >> 1)] = pack2(a, other);
  __syncthreads();
  float nb = 0.f;
#pragma unroll
  for (int d = 0; d < DD; ++d) nb += hl[w][d] * bn2[d * DD + f];
  nbias[(size_t)n * DD + f] = nb;
}

// ---------------- edge MLP layer1 -> hn1c, chunk-major CSR order ----------------
// hn1c[((j>>3)*EE + pos)*8 + (j&7)] : chunk c holds pairs c*8..c*8+7 of each edge.
__global__ void k_edgemlp(const float* __restrict__ ea, const float* __restrict__ Wn1,
                          const float* __restrict__ bn1, const int* __restrict__ epos,
                          uint_t* __restrict__ hn1c) {
  int idx = blockIdx.x * 256 + threadIdx.x;  // e*64 + j
  if (idx >= EE * (K1 / 2)) return;
  int e = idx >> 6, j = idx & 63;
  int k0 = 2 * j, k1 = 2 * j + 1;
  float a0 = ea[e * 4 + 0], a1 = ea[e * 4 + 1], a2 = ea[e * 4 + 2], a3 = ea[e * 4 + 3];
  float t0 = bn1[k0] + a0 * Wn1[k0] + a1 * Wn1[K1 + k0] + a2 * Wn1[2 * K1 + k0] + a3 * Wn1[3 * K1 + k0];
  float t1 = bn1[k1] + a0 * Wn1[k1] + a1 * Wn1[K1 + k1] + a2 * Wn1[2 * K1 + k1] + a3 * Wn1[3 * K1 + k1];
  int pos = epos[e];
  hn1c[((size_t)(j >> 3) * EE + pos) * 8 + (j & 7)] = pack2(siluf_(t0), siluf_(t1));
}

// ---------------- src-CSR build ----------------
__global__ void k_hist(const int* __restrict__ ei, int* __restrict__ cnt_s) {
  int e = blockIdx.x * 256 + threadIdx.x;
  if (e >= EE) return;
  atomicAdd(&cnt_s[ei[e]], 1);
}

__global__ void k_scan(const int* __restrict__ cnt, int* __restrict__ rp,
                       const int* __restrict__ batch, int* __restrict__ goff) {
  if (blockIdx.x == 1) {
    int g = threadIdx.x;
    if (g > BB) return;
    int lo = 0, hi = NN;
    while (lo < hi) {
      int mid = (lo + hi) >> 1;
      if (batch[mid] < g) lo = mid + 1; else hi = mid;
    }
    goff[g] = lo;
    return;
  }
  __shared__ int part[1024];
  const int tid = threadIdx.x;
  const int chunk = (NN + 1023) / 1024;
  int s = 0;
  for (int j = 0; j < chunk; ++j) {
    int idx = tid * chunk + j;
    if (idx < NN) s += cnt[idx];
  }
  part[tid] = s;
  __syncthreads();
  for (int off = 1; off < 1024; off <<= 1) {
    int v = (tid >= off) ? part[tid - off] : 0;
    __syncthreads();
    part[tid] += v;
    __syncthreads();
  }
  int base = (tid == 0) ? 0 : part[tid - 1];
  for (int j = 0; j < chunk; ++j) {
    int idx = tid * chunk + j;
    if (idx < NN) { rp[idx] = base; base += cnt[idx]; }
  }
  if (tid == 1023) rp[NN] = part[1023];
}

__global__ void k_fill(const int* __restrict__ ei, const int* __restrict__ rps,
                       int* __restrict__ cur_s, int* __restrict__ epos,
                       int* __restrict__ esd) {
  int e = blockIdx.x * 256 + threadIdx.x;
  if (e >= EE) return;
  int s = ei[e], d = ei[EE + e];
  int ps = atomicAdd(&cur_s[s], 1);
  int pos = rps[s] + ps;
  epos[e] = pos;
  esd[2 * pos] = s;
  esd[2 * pos + 1] = d;
}

// ---------------- fused NNConv message kernel ----------------
// Grid: CSPL*625 = 2500 blocks (quarter-split), 512 threads. vs R13 (53.4us,
// latency-bound at 31% occupancy): finer K-split doubles block parallelism,
// per-block barrier chain 9 -> 5, LDS 46 -> ~39KB -> 4 blk/CU. Costs 4 atomic
// commits/edge (WRITE 20->40MB) — R4/R6 proved write traffic off critical path.
// Addressing/structure bit-identical to the proven R3 framework otherwise.
__global__ __launch_bounds__(512, 4) void k_conv(
    const uint_t* __restrict__ hpk, const uint_t* __restrict__ hn1c,
    const uint_t* __restrict__ Wn2m, const float* __restrict__ nbias,
    const int* __restrict__ rps, const int* __restrict__ esd,
    float* __restrict__ aggr) {
  __shared__ __align__(16) uint_t Gp[NPB * 2 * 64 * 4];  // 32 KB
  __shared__ __align__(16) uint_t eh[CPB * EHW];         // 6 KB staged hn1c
  __shared__ int2 eStage[ECREG];                         // 768 B
  const int tid = threadIdx.x;
  const int w = tid >> 6, lane = tid & 63;
  const int q = lane >> 4, n16 = lane & 15;
  const int half = blockIdx.x / 625;   // K-quarter 0..3
  const int ng = blockIdx.x - half * 625;
  const int n0 = ng * NPB;
  const int e0 = rps[n0], e1 = rps[n0 + NPB];
  const int ecnt = e1 - e0;
  const int ecap = ecnt < ECREG ? ecnt : ECREG;

  if (tid < ECREG && tid < ecnt) eStage[tid] = ((const int2*)esd)[e0 + tid];

  // ---- issue hn1c staging loads early; thread tid owns 16B at chunk uint off tid*4 ----
  uint4 st0, st1;
  const bool stv = (tid < ecap * 2);
  if (stv) {
    const size_t base = ((size_t)(half * CPB) * EE + e0) * 8;
    st0 = ((const uint4*)(hn1c + base))[tid];
    st1 = ((const uint4*)(hn1c + base + (size_t)EE * 8))[tid];
  }

  FragU a0, a1;
  {
    const uint4* ap = (const uint4*)(hpk + (size_t)(n0 + n16) * 32);
    a0.u = ap[q];
    a1.u = ap[4 + q];
  }
  __syncthreads();  // eStage visible

  // seed register accumulators (nbias on quarter 0) — overlaps with staging latency
  float acc[ESLOT];
#pragma unroll
  for (int s = 0; s < ESLOT; ++s) {
    const int li = w + 8 * s;
    float v = 0.f;
    if (half == 0 && li < ecap)
      v = nbias[(size_t)eStage[li].x * 64 + lane];
    acc[s] = v;
  }

  // ---- write staged chunks to LDS (linear layout; read after next barrier) ----
  if (stv) {
    ((uint4*)(eh + 0 * EHW))[tid] = st0;
    ((uint4*)(eh + 1 * EHW))[tid] = st1;
  }

  const int kq = w >> 2, fcw = w & 3;
  for (int cc = 0; cc < CPB; ++cc) {
    const int c = half * CPB + cc;
    if (cc) __syncthreads();  // prior phase-2 reads done
    // ---- phase 1: wave (kq,fcw) computes slots 0..3, writes b128 ----
    uint_t pk[4][4];  // [r][slot], fully unrolled -> registers
#pragma unroll
    for (int slot = 0; slot < 4; ++slot) {
      const int kpg = c * 8 + kq * 4 + slot;
      const uint4* bp = (const uint4*)Wn2m + (size_t)(kpg * 4 + fcw) * 256 + lane;
      FragU b00, b01, b10, b11;
      b00.u = bp[0];    // par0 hf0
      b01.u = bp[64];   // par0 hf1
      b10.u = bp[128];  // par1 hf0
      b11.u = bp[192];  // par1 hf1
      f32x4_t acc0 = {0.f, 0.f, 0.f, 0.f};
      f32x4_t acc1 = {0.f, 0.f, 0.f, 0.f};
      acc0 = __builtin_amdgcn_mfma_f32_16x16x32_bf16(a0.b, b00.b, acc0, 0, 0, 0);
      acc0 = __builtin_amdgcn_mfma_f32_16x16x32_bf16(a1.b, b01.b, acc0, 0, 0, 0);
      acc1 = __builtin_amdgcn_mfma_f32_16x16x32_bf16(a0.b, b10.b, acc1, 0, 0, 0);
      acc1 = __builtin_amdgcn_mfma_f32_16x16x32_bf16(a1.b, b11.b, acc1, 0, 0, 0);
#pragma unroll
      for (int r = 0; r < 4; ++r) pk[r][slot] = pack2(acc0[r], acc1[r]);
    }
#pragma unroll
    for (int r = 0; r < 4; ++r) {
      const int m = q * 4 + r;  // D row = node index
      uint4 v;
      v.x = pk[r][0]; v.y = pk[r][1]; v.z = pk[r][2]; v.w = pk[r][3];
      ((uint4*)Gp)[(size_t)(m * 2 + kq) * 64 + fcw * 16 + n16] = v;
    }
    __syncthreads();  // Gp ready; eh writes ordered before first phase-2 read
    // ---- phase 2: register-resident edge partials (hv from LDS broadcast) ----
    const uint4* ehb = (const uint4*)(eh + cc * EHW);
#pragma unroll
    for (int s = 0; s < ESLOT; ++s) {
      const int li = w + 8 * s;
      if (li < ecap) {
        const int2 sd = eStage[li];
        const int m = sd.x - n0;
        uint4 hv0 = ehb[li * 2], hv1 = ehb[li * 2 + 1];
        const uint4* gb = (const uint4*)Gp + (size_t)(m * 2) * 64 + lane;
        uint4 g0 = gb[0], g1 = gb[64];
        float p = acc[s];
        p = dot2a(g0.x, hv0.x, p);
        p = dot2a(g0.y, hv0.y, p);
        p = dot2a(g0.z, hv0.z, p);
        p = dot2a(g0.w, hv0.w, p);
        p = dot2a(g1.x, hv1.x, p);
        p = dot2a(g1.y, hv1.y, p);
        p = dot2a(g1.z, hv1.z, p);
        p = dot2a(g1.w, hv1.w, p);
        acc[s] = p;
      }
    }
    // overflow edges (virtually never): per-chunk atomic path, global hn1c
    for (int li = ECREG + w; li < ecnt; li += 8) {
      const int ii = e0 + li;
      const int src = __builtin_amdgcn_readfirstlane(esd[2 * ii]);
      const int dst = __builtin_amdgcn_readfirstlane(esd[2 * ii + 1]);
      const int m = src - n0;
      float p = (half == 0 && cc == 0) ? nbias[(size_t)src * 64 + lane] : 0.f;
      const uint4* hp = (const uint4*)(hn1c + ((size_t)c * EE + ii) * 8);
      uint4 hv0 = hp[0], hv1 = hp[1];
      const uint4* gb = (const uint4*)Gp + (size_t)(m * 2) * 64 + lane;
      uint4 g0 = gb[0], g1 = gb[64];
      p = dot2a(g0.x, hv0.x, p);
      p = dot2a(g0.y, hv0.y, p);
      p = dot2a(g0.z, hv0.z, p);
      p = dot2a(g0.w, hv0.w, p);
      p = dot2a(g1.x, hv1.x, p);
      p = dot2a(g1.y, hv1.y, p);
      p = dot2a(g1.z, hv1.z, p);
      p = dot2a(g1.w, hv1.w, p);
      atomicAdd(&aggr[(size_t)dst * 64 + lane], p);
    }
  }
  // ---- commit: one atomic per register-tracked edge per quarter ----
#pragma unroll
  for (int s = 0; s < ESLOT; ++s) {
    const int li = w + 8 * s;
    if (li < ecap) {
      const int dst = eStage[li].y;
      atomicAdd(&aggr[(size_t)dst * 64 + lane], acc[s]);
    }
  }
}

// ---------------- h update: 4 nodes/block; residual + aggr + root GEMM; re-zeros aggr ----------------
// Last layer (l==LL-1): hpk/nbias are dead -> skip their compute+writes.
__global__ __launch_bounds__(256) void k_update(
    float* __restrict__ h, uint_t* __restrict__ hpk,
    float* __restrict__ aggr, const float* __restrict__ bn2,
    const float* __restrict__ root, const float* __restrict__ cb,
    float* __restrict__ nbias, int l) {
  __shared__ float hl[4][DD];
  __shared__ float al[4][DD];
  const int tid = threadIdx.x, w = tid >> 6, f = tid & 63;
  const int n = blockIdx.x * 4 + w;
  float hv = h[(size_t)n * DD + f];
  hl[w][f] = hv;
  float acc = hv + aggr[(size_t)n * DD + f] + cb[l * DD + f];
  aggr[(size_t)n * DD + f] = 0.f;
  __syncthreads();
  const float* rp = root + (size_t)l * DD2;
#pragma unroll
  for (int d = 0; d < DD; ++d) acc += hl[w][d] * rp[d * DD + f];
  h[(size_t)n * DD + f] = acc;
  if (l == LL - 1) return;  // hpk/nbias dead after last conv layer
  al[w][f] = acc;
  float other = __shfl_down(acc, 1);
  if ((f & 1) == 0)
    hpk[(size_t)n * 32 + (f >> 1)] = pack2(acc, other);
  __syncthreads();
  float nb = 0.f;
#pragma unroll
  for (int d = 0; d < DD; ++d) nb += al[w][d] * bn2[d * DD + f];
  nbias[(size_t)n * DD + f] = nb;
}

// ---------------- fused Set2Set (3x LSTM+attention) + output MLP ----------------
// Wave-parallel attention (R8): wave w computes node base+w's dot with a
// coalesced 64-lane load + shuffle reduce; wave 0 does max/exp/sum.
#define EVCAP 2048
__global__ void k_s2s(const float* __restrict__ h, const int* __restrict__ goff,
                      const float* __restrict__ Wiht, const float* __restrict__ Whht,
                      const float* __restrict__ lb,
                      const float* __restrict__ Wo1, const float* __restrict__ bo1,
                      const float* __restrict__ Wo2, const float* __restrict__ bo2,
                      void* __restrict__ outv, const int* __restrict__ flag) {
  __shared__ float qsl[K1];
  __shared__ float hsl[DD];
  __shared__ float csl[DD];
  __shared__ float gl[4][DD];
  __shared__ float ev[EVCAP];
  __shared__ float rp4[4][DD];
  __shared__ float smax, ssum;
  const int g = blockIdx.x, tid = threadIdx.x;
  const int w = tid >> 6, lane = tid & 63;

  if (tid < K1) qsl[tid] = 0.f;
  else if (tid < K1 + DD) hsl[tid - K1] = 0.f;
  else csl[tid - K1 - DD] = 0.f;
  __syncthreads();

  const int i0 = goff[g];
  int cnt = goff[g + 1] - i0;
  if (cnt > EVCAP) cnt = EVCAP;

  for (int m = 0; m < MM; ++m) {
    {
      float a = lb[tid];
      for (int i = 0; i < K1; ++i) a += qsl[i] * Wiht[i * 256 + tid];
      for (int i = 0; i < DD; ++i) a += hsl[i] * Whht[i * 256 + tid];
      gl[tid >> 6][tid & 63] = a;
    }
    __syncthreads();
    if (tid < DD) {
      float ig = sigmf_(gl[0][tid]), fg = sigmf_(gl[1][tid]);
      float gg = tanhf(gl[2][tid]), og = sigmf_(gl[3][tid]);
      float c = fg * csl[tid] + ig * gg;
      csl[tid] = c;
      hsl[tid] = og * tanhf(c);
    }
    __syncthreads();
    const float qv = hsl[lane];
    for (int base = 0; base < cnt; base += 4) {
      const int j = base + w;
      float e = 0.f;
      if (j < cnt) e = h[(size_t)(i0 + j) * DD + lane] * qv;
#pragma unroll
      for (int off = 32; off > 0; off >>= 1) e += __shfl_down(e, off);
      if (lane == 0 && j < cnt) ev[j] = e;
    }
    __syncthreads();
    if (w == 0) {
      float lm = -1e30f;
      for (int jj = lane; jj < cnt; jj += 64) lm = fmaxf(lm, ev[jj]);
#pragma unroll
      for (int off = 32; off > 0; off >>= 1) lm = fmaxf(lm, __shfl_down(lm, off));
      const float emax = __shfl(lm, 0);
      float ls = 0.f;
      for (int jj = lane; jj < cnt; jj += 64) {
        float ex = expf(ev[jj] - emax);
        ev[jj] = ex;
        ls += ex;
      }
#pragma unroll
      for (int off = 32; off > 0; off >>= 1) ls += __shfl_down(ls, off);
      if (lane == 0) { smax = emax; ssum = ls; }
    }
    __syncthreads();
    const float denom = ssum;
    float racc = 0.f;
    for (int jj = w; jj < cnt; jj += 4)
      racc += ev[jj] * h[(size_t)(i0 + jj) * DD + lane];
    rp4[w][lane] = racc;
    __syncthreads();
    if (tid < DD) {
      float r = rp4[0][tid] + rp4[1][tid] + rp4[2][tid] + rp4[3][tid];
      r = (cnt > 0 && denom > 0.f) ? r / denom : 0.f;
      qsl[tid] = hsl[tid];
      qsl[DD + tid] = r;
    }
    __syncthreads();
  }
  if (tid < DD) {
    float t = bo1[tid];
    for (int i = 0; i < K1; ++i) t += qsl[i] * Wo1[i * DD + tid];
    float s = siluf_(t) * Wo2[tid];
    for (int off = 32; off > 0; off >>= 1) s += __shfl_down(s, off);
    if (tid == 0) {
      float v = s + bo2[0];
      if (*flag) ((ushort_t*)outv)[g] = f2bf(v);
      else       ((float*)outv)[g] = v;
    }
  }
}

extern "C" void kernel_launch(void* const* d_in, const int* in_sizes, int n_in,
                              void* d_out, int out_size, void* d_ws, size_t ws_size,
                              hipStream_t stream) {
  const void* x_r    = d_in[0];
  const int*  ei     = (const int*)d_in[1];
  const void* ea_r   = d_in[2];
  const int*  batch  = (const int*)d_in[3];
  const void* W0_r   = d_in[4];
  const void* b0_r   = d_in[5];
  const void* Wn1_r  = d_in[6];
  const void* bn1_r  = d_in[7];
  const void* Wn2_r  = d_in[8];
  const void* bn2_r  = d_in[9];
  const void* root_r = d_in[10];
  const void* cb_r   = d_in[11];
  const void* Wih_r  = d_in[12];
  const void* Whh_r  = d_in[13];
  const void* lb_r   = d_in[14];
  const void* Wo1_r  = d_in[15];
  const void* bo1_r  = d_in[16];
  const void* Wo2_r  = d_in[17];
  const void* bo2_r  = d_in[18];

  char* w = (char*)d_ws;
  size_t off = 0;
  auto alloc = [&](size_t bytes) -> void* {
    void* p = w + off;
    off = (off + bytes + 255) & ~(size_t)255;
    return p;
  };
  int* flag = (int*)alloc(4);
  float* xc    = (float*)alloc((size_t)NN * DIN_ * 4);
  float* eac   = (float*)alloc((size_t)EE * 4 * 4);
  float* W0c   = (float*)alloc((size_t)DIN_ * DD * 4);
  float* b0c   = (float*)alloc((size_t)DD * 4);
  float* Wn1c  = (float*)alloc((size_t)4 * K1 * 4);
  float* bn1c  = (float*)alloc((size_t)K1 * 4);
  float* bn2c  = (float*)alloc((size_t)DD2 * 4);
  float* rootc = (float*)alloc((size_t)LL * DD2 * 4);
  float* cbc   = (float*)alloc((size_t)LL * DD * 4);
  float* Wihc  = (float*)alloc((size_t)4 * DD * K1 * 4);
  float* Whhc  = (float*)alloc((size_t)4 * DD * DD * 4);
  float* lbc   = (float*)alloc((size_t)4 * DD * 4);
  float* Wo1c  = (float*)alloc((size_t)K1 * DD * 4);
  float* bo1c  = (float*)alloc((size_t)DD * 4);
  float* Wo2c  = (float*)alloc((size_t)DD * 4);
  float* bo2c  = (float*)alloc((size_t)4);
  float* Wiht  = (float*)alloc((size_t)K1 * 256 * 4);
  float* Whht  = (float*)alloc((size_t)DD * 256 * 4);
  uint_t* Wn2m = (uint_t*)alloc((size_t)64 * 4 * 2 * 2 * 64 * 4 * 4);  // 1 MB
  float*  h    = (float*)alloc((size_t)NN * DD * 4);
  uint_t* hpk  = (uint_t*)alloc((size_t)NN * 32 * 4);
  uint_t* hn1c = (uint_t*)alloc((size_t)EE * (K1 / 2) * 4);  // chunk-major
  float*  aggr = (float*)alloc((size_t)NN * DD * 4);
  float*  nbias= (float*)alloc((size_t)NN * DD * 4);
  int* cnts  = (int*)alloc((size_t)2 * NN * 4);
  int* rps   = (int*)alloc((size_t)(NN + 1) * 4);
  int* epos  = (int*)alloc((size_t)EE * 4);
  int* esd   = (int*)alloc((size_t)2 * EE * 4);
  int* goff  = (int*)alloc((size_t)(BB + 1) * 4);

  int* cnt_s = cnts;
  int* cur_s = cnts + NN;

  hipMemsetAsync(cnts, 0, (size_t)2 * NN * 4, stream);
  hipMemsetAsync(aggr, 0, (size_t)NN * DD * 4, stream);

  CanonArgs ca;
  const void* srcs[NCANON] = {x_r, ea_r, W0_r, b0_r, Wn1_r, bn1_r, bn2_r, root_r,
                              cb_r, Wih_r, Whh_r, lb_r, Wo1_r, bo1_r, Wo2_r, bo2_r};
  float* dsts[NCANON] = {xc, eac, W0c, b0c, Wn1c, bn1c, bn2c, rootc,
                         cbc, Wihc, Whhc, lbc, Wo1c, bo1c, Wo2c, bo2c};
  int cnts_c[NCANON] = {NN * DIN_, EE * 4, DIN_ * DD, DD, 4 * K1, K1, DD2, LL * DD2,
                        LL * DD, 4 * DD * K1, 4 * DD * DD, 4 * DD, K1 * DD, DD, DD, 1};
  for (int i = 0; i < NCANON; ++i) { ca.src[i] = srcs[i]; ca.dst[i] = dsts[i]; ca.n[i] = cnts_c[i]; }
  {
    dim3 grid((EE * 4 + 255) / 256, NCANON);
    k_canon<<<grid, 256, 0, stream>>>(ca, (const ushort_t*)ea_r, flag);
  }
  k_wn2m<<<K1, 256, 0, stream>>>(Wn2_r, Wn2m, flag);
  k_wT<<<(4 * DD * K1 + 255) / 256, 256, 0, stream>>>(Wihc, Whhc, Wiht, Whht);

  k_embed<<<NN / 4, 256, 0, stream>>>(xc, W0c, b0c, bn2c, h, hpk, nbias);
  k_hist<<<(EE + 255) / 256, 256, 0, stream>>>(ei, cnt_s);
  k_scan<<<2, 1024, 0, stream>>>(cnt_s, rps, batch, goff);
  k_fill<<<(EE + 255) / 256, 256, 0, stream>>>(ei, rps, cur_s, epos, esd);
  k_edgemlp<<<(EE * (K1 / 2) + 255) / 256, 256, 0, stream>>>(eac, Wn1c, bn1c, epos, hn1c);

  for (int l = 0; l < LL; ++l) {
    k_conv<<<CSPL * (NN / NPB), 512, 0, stream>>>(hpk, hn1c, Wn2m, nbias, rps, esd, aggr);
    k_update<<<NN / 4, 256, 0, stream>>>(h, hpk, aggr, bn2c, rootc, cbc, nbias, l);
  }

  k_s2s<<<BB, 256, 0, stream>>>(h, goff, Wiht, Whht, lbc, Wo1c, bo1c, Wo2c, bo2c,
                                d_out, flag);
}

// Round 15
// 397.485 us; speedup vs baseline: 1.1356x; 1.1356x over previous
//
#include <hip/hip_runtime.h>
#include <cstdint>
#include <cstddef>

#define NN   10000
#define EE   40000
#define DIN_ 11
#define DD   64
#define LL   4
#define BB   512
#define MM   3
#define K1   128   // 2*D
#define DD2  4096  // D*D
#define NPB  16    // nodes per k_conv block
#define CSPL 2     // chunk-split across blocks (measured optimum: 1->68us, 2->53us, 4->64us)
#define CPB  4     // chunks per block = NCH / CSPL
#define ESLOT 12   // register-accumulated edge slots per wave
#define ECREG (8 * ESLOT)  // 96 register-tracked edges per block
#define EHW (ECREG * 8)    // uints per staged hn1c chunk buffer

typedef unsigned short ushort_t;
typedef unsigned int   uint_t;

typedef __bf16 bf16x8_t __attribute__((ext_vector_type(8)));
typedef float  f32x4_t  __attribute__((ext_vector_type(4)));
union FragU { uint4 u; bf16x8_t b; };

__device__ __forceinline__ float bfu(ushort_t u) { return __uint_as_float(((uint_t)u) << 16); }
__device__ __forceinline__ float bflo(uint_t u) { return __uint_as_float(u << 16); }
__device__ __forceinline__ float bfhi(uint_t u) { return __uint_as_float(u & 0xffff0000u); }
__device__ __forceinline__ ushort_t f2bf(float f) {
  uint_t u = __float_as_uint(f);
  u = (u + 0x7fffu + ((u >> 16) & 1u)) >> 16;
  return (ushort_t)u;
}
__device__ __forceinline__ uint_t pack2(float lo, float hi) {
  return (uint_t)f2bf(lo) | ((uint_t)f2bf(hi) << 16);
}
__device__ __forceinline__ float sigmf_(float x) { return 1.f / (1.f + expf(-x)); }
__device__ __forceinline__ float siluf_(float x) { return x / (1.f + expf(-x)); }

#if defined(__HIP_DEVICE_COMPILE__) && __has_builtin(__builtin_amdgcn_fdot2_f32_bf16)
typedef __bf16 bf16x2_t __attribute__((ext_vector_type(2)));
__device__ __forceinline__ float dot2a(uint_t a, uint_t b, float c) {
  union { uint_t u; bf16x2_t v; } ua, ub;
  ua.u = a; ub.u = b;
  return __builtin_amdgcn_fdot2_f32_bf16(ua.v, ub.v, c, false);
}
#else
__device__ __forceinline__ float dot2a(uint_t a, uint_t b, float c) {
  return c + bflo(a) * bflo(b) + bfhi(a) * bfhi(b);
}
#endif

// ---------------- canonicalize float inputs to fp32 (self-detecting dtype) ----------------
#define NCANON 16
struct CanonArgs {
  const void* src[NCANON];
  float* dst[NCANON];
  int n[NCANON];
};
__global__ void k_canon(CanonArgs a, const ushort_t* __restrict__ ea, int* __restrict__ flag) {
  __shared__ int bad;
  if (threadIdx.x == 0) bad = 0;
  __syncthreads();
  ushort_t u = ea[threadIdx.x];
  if ((u & 0x8000u) || u > 0x3F80u) atomicAdd(&bad, 1);
  __syncthreads();
  const int isbf = (bad == 0) ? 1 : 0;
  if (blockIdx.x == 0 && blockIdx.y == 0 && threadIdx.x == 0) *flag = isbf;
  const int ai = blockIdx.y;
  const int n = a.n[ai];
  const int i = blockIdx.x * 256 + threadIdx.x;
  if (i >= n) return;
  float v;
  if (isbf) v = bfu(((const ushort_t*)a.src[ai])[i]);
  else      v = ((const float*)a.src[ai])[i];
  a.dst[ai][i] = v;
}

// ---------------- Wn2 repack into MFMA B-fragment order (coalesced) ----------------
__global__ void k_wn2m(const void* __restrict__ Wn2, uint_t* __restrict__ out,
                       const int* __restrict__ flag) {
  __shared__ ushort_t row[DD2];  // 8 KB
  const int k = blockIdx.x, tid = threadIdx.x;
  if (*flag) {
    const uint4* src = (const uint4*)((const ushort_t*)Wn2 + (size_t)k * DD2);
    ((uint4*)row)[tid] = src[tid];
    ((uint4*)row)[tid + 256] = src[tid + 256];
  } else {
    const float* src = (const float*)Wn2 + (size_t)k * DD2;
    for (int j = 0; j < 16; ++j) row[tid + 256 * j] = f2bf(src[tid + 256 * j]);
  }
  __syncthreads();
  const int kpg = k >> 1, par = k & 1;
  const int lane = tid >> 2, jp = tid & 3;
  const int q = lane >> 4, n = lane & 15;
  for (int fc = 0; fc < 4; ++fc) {
#pragma unroll
    for (int hf = 0; hf < 2; ++hf) {
      int d0 = hf * 32 + q * 8 + 2 * jp;
      int f = fc * 16 + n;
      uint_t lo = row[d0 * 64 + f], hi = row[(d0 + 1) * 64 + f];
      out[((((size_t)kpg * 4 + fc) * 2 + par) * 2 + hf) * 256 + tid] = lo | (hi << 16);
    }
  }
}

// ---------------- LSTM weight transpose: Wiht[i][j], Whht[i][j] ----------------
__global__ void k_wT(const float* __restrict__ Wihc, const float* __restrict__ Whhc,
                     float* __restrict__ Wiht, float* __restrict__ Whht) {
  int idx = blockIdx.x * 256 + threadIdx.x;
  if (idx < 4 * DD * K1) {
    int j = idx >> 7, i = idx & 127;  // Wihc[j][i]
    Wiht[i * 256 + j] = Wihc[idx];
  }
  if (idx < 4 * DD * DD) {
    int j = idx >> 6, i = idx & 63;   // Whhc[j][i]
    Whht[i * 256 + j] = Whhc[idx];
  }
}

// ---------------- node embed: 4 nodes/block; h, hpk, nbias ----------------
__global__ __launch_bounds__(256) void k_embed(
    const float* __restrict__ x, const float* __restrict__ W0,
    const float* __restrict__ b0, const float* __restrict__ bn2,
    float* __restrict__ h, uint_t* __restrict__ hpk,
    float* __restrict__ nbias) {
  __shared__ float xs[4][DIN_];
  __shared__ float hl[4][DD];
  const int tid = threadIdx.x, w = tid >> 6, f = tid & 63;
  const int n = blockIdx.x * 4 + w;
  if (f < DIN_) xs[w][f] = x[n * DIN_ + f];
  __syncthreads();
  float a = b0[f];
  for (int i = 0; i < DIN_; ++i) a += xs[w][i] * W0[i * DD + f];
  h[(size_t)n * DD + f] = a;
  hl[w][f] = a;
  float other = __shfl_down(a, 1);
  if ((f & 1) == 0)
    hpk[(size_t)n * 32 + (f >> 1)] = pack2(a, other);
  __syncthreads();
  float nb = 0.f;
#pragma unroll
  for (int d = 0; d < DD; ++d) nb += hl[w][d] * bn2[d * DD + f];
  nbias[(size_t)n * DD + f] = nb;
}

// ---------------- edge MLP layer1 -> hn1c, chunk-major CSR order ----------------
// hn1c[((j>>3)*EE + pos)*8 + (j&7)] : chunk c holds pairs c*8..c*8+7 of each edge.
__global__ void k_edgemlp(const float* __restrict__ ea, const float* __restrict__ Wn1,
                          const float* __restrict__ bn1, const int* __restrict__ epos,
                          uint_t* __restrict__ hn1c) {
  int idx = blockIdx.x * 256 + threadIdx.x;  // e*64 + j
  if (idx >= EE * (K1 / 2)) return;
  int e = idx >> 6, j = idx & 63;
  int k0 = 2 * j, k1 = 2 * j + 1;
  float a0 = ea[e * 4 + 0], a1 = ea[e * 4 + 1], a2 = ea[e * 4 + 2], a3 = ea[e * 4 + 3];
  float t0 = bn1[k0] + a0 * Wn1[k0] + a1 * Wn1[K1 + k0] + a2 * Wn1[2 * K1 + k0] + a3 * Wn1[3 * K1 + k0];
  float t1 = bn1[k1] + a0 * Wn1[k1] + a1 * Wn1[K1 + k1] + a2 * Wn1[2 * K1 + k1] + a3 * Wn1[3 * K1 + k1];
  int pos = epos[e];
  hn1c[((size_t)(j >> 3) * EE + pos) * 8 + (j & 7)] = pack2(siluf_(t0), siluf_(t1));
}

// ---------------- src-CSR build ----------------
__global__ void k_hist(const int* __restrict__ ei, int* __restrict__ cnt_s) {
  int e = blockIdx.x * 256 + threadIdx.x;
  if (e >= EE) return;
  atomicAdd(&cnt_s[ei[e]], 1);
}

__global__ void k_scan(const int* __restrict__ cnt, int* __restrict__ rp,
                       const int* __restrict__ batch, int* __restrict__ goff) {
  if (blockIdx.x == 1) {
    int g = threadIdx.x;
    if (g > BB) return;
    int lo = 0, hi = NN;
    while (lo < hi) {
      int mid = (lo + hi) >> 1;
      if (batch[mid] < g) lo = mid + 1; else hi = mid;
    }
    goff[g] = lo;
    return;
  }
  __shared__ int part[1024];
  const int tid = threadIdx.x;
  const int chunk = (NN + 1023) / 1024;
  int s = 0;
  for (int j = 0; j < chunk; ++j) {
    int idx = tid * chunk + j;
    if (idx < NN) s += cnt[idx];
  }
  part[tid] = s;
  __syncthreads();
  for (int off = 1; off < 1024; off <<= 1) {
    int v = (tid >= off) ? part[tid - off] : 0;
    __syncthreads();
    part[tid] += v;
    __syncthreads();
  }
  int base = (tid == 0) ? 0 : part[tid - 1];
  for (int j = 0; j < chunk; ++j) {
    int idx = tid * chunk + j;
    if (idx < NN) { rp[idx] = base; base += cnt[idx]; }
  }
  if (tid == 1023) rp[NN] = part[1023];
}

__global__ void k_fill(const int* __restrict__ ei, const int* __restrict__ rps,
                       int* __restrict__ cur_s, int* __restrict__ epos,
                       int* __restrict__ esd) {
  int e = blockIdx.x * 256 + threadIdx.x;
  if (e >= EE) return;
  int s = ei[e], d = ei[EE + e];
  int ps = atomicAdd(&cur_s[s], 1);
  int pos = rps[s] + ps;
  epos[e] = pos;
  esd[2 * pos] = s;
  esd[2 * pos + 1] = d;
}

// ---------------- fused NNConv message kernel (converged structure, 53.4us) ----------------
// Grid: CSPL*625, 512 threads. Unconditional strided slots (li=w+8s): every
// LDS read compile-time addressable -> fully pipelined. 64 VGPR, no spills.
// Measured & rejected: edge-major layout (R4), CSPL=1 (R6), CSPL=4 (R14),
// conditional g-reuse (R7), padded per-node slots (R9/R10), scalar hv (R12).
__global__ __launch_bounds__(512, 4) void k_conv(
    const uint_t* __restrict__ hpk, const uint_t* __restrict__ hn1c,
    const uint_t* __restrict__ Wn2m, const float* __restrict__ nbias,
    const int* __restrict__ rps, const int* __restrict__ esd,
    float* __restrict__ aggr) {
  __shared__ __align__(16) uint_t Gp[NPB * 2 * 64 * 4];  // 32 KB
  __shared__ __align__(16) uint_t eh[CPB * EHW];         // 12 KB staged hn1c
  __shared__ int2 eStage[ECREG];                         // 768 B
  const int tid = threadIdx.x;
  const int w = tid >> 6, lane = tid & 63;
  const int q = lane >> 4, n16 = lane & 15;
  const int half = blockIdx.x / 625;
  const int ng = blockIdx.x - half * 625;
  const int n0 = ng * NPB;
  const int e0 = rps[n0], e1 = rps[n0 + NPB];
  const int ecnt = e1 - e0;
  const int ecap = ecnt < ECREG ? ecnt : ECREG;

  if (tid < ECREG && tid < ecnt) eStage[tid] = ((const int2*)esd)[e0 + tid];

  // ---- issue hn1c staging loads early; thread tid owns 16B at chunk uint off tid*4 ----
  uint4 st0, st1, st2, st3;
  const bool stv = (tid < ecap * 2);
  if (stv) {
    const size_t base = ((size_t)(half * CPB) * EE + e0) * 8;
    st0 = ((const uint4*)(hn1c + base))[tid];
    st1 = ((const uint4*)(hn1c + base + (size_t)EE * 8))[tid];
    st2 = ((const uint4*)(hn1c + base + (size_t)2 * EE * 8))[tid];
    st3 = ((const uint4*)(hn1c + base + (size_t)3 * EE * 8))[tid];
  }

  FragU a0, a1;
  {
    const uint4* ap = (const uint4*)(hpk + (size_t)(n0 + n16) * 32);
    a0.u = ap[q];
    a1.u = ap[4 + q];
  }
  __syncthreads();  // eStage visible

  // seed register accumulators (nbias on half 0) — overlaps with staging latency
  float acc[ESLOT];
#pragma unroll
  for (int s = 0; s < ESLOT; ++s) {
    const int li = w + 8 * s;
    float v = 0.f;
    if (half == 0 && li < ecap)
      v = nbias[(size_t)eStage[li].x * 64 + lane];
    acc[s] = v;
  }

  // ---- write staged chunks to LDS (linear layout; read after next barrier) ----
  if (stv) {
    ((uint4*)(eh + 0 * EHW))[tid] = st0;
    ((uint4*)(eh + 1 * EHW))[tid] = st1;
    ((uint4*)(eh + 2 * EHW))[tid] = st2;
    ((uint4*)(eh + 3 * EHW))[tid] = st3;
  }

  const int kq = w >> 2, fcw = w & 3;
  for (int cc = 0; cc < CPB; ++cc) {
    const int c = half * CPB + cc;
    if (cc) __syncthreads();  // prior phase-2 reads done
    // ---- phase 1: wave (kq,fcw) computes slots 0..3, writes b128 ----
    uint_t pk[4][4];  // [r][slot], fully unrolled -> registers
#pragma unroll
    for (int slot = 0; slot < 4; ++slot) {
      const int kpg = c * 8 + kq * 4 + slot;
      const uint4* bp = (const uint4*)Wn2m + (size_t)(kpg * 4 + fcw) * 256 + lane;
      FragU b00, b01, b10, b11;
      b00.u = bp[0];    // par0 hf0
      b01.u = bp[64];   // par0 hf1
      b10.u = bp[128];  // par1 hf0
      b11.u = bp[192];  // par1 hf1
      f32x4_t acc0 = {0.f, 0.f, 0.f, 0.f};
      f32x4_t acc1 = {0.f, 0.f, 0.f, 0.f};
      acc0 = __builtin_amdgcn_mfma_f32_16x16x32_bf16(a0.b, b00.b, acc0, 0, 0, 0);
      acc0 = __builtin_amdgcn_mfma_f32_16x16x32_bf16(a1.b, b01.b, acc0, 0, 0, 0);
      acc1 = __builtin_amdgcn_mfma_f32_16x16x32_bf16(a0.b, b10.b, acc1, 0, 0, 0);
      acc1 = __builtin_amdgcn_mfma_f32_16x16x32_bf16(a1.b, b11.b, acc1, 0, 0, 0);
#pragma unroll
      for (int r = 0; r < 4; ++r) pk[r][slot] = pack2(acc0[r], acc1[r]);
    }
#pragma unroll
    for (int r = 0; r < 4; ++r) {
      const int m = q * 4 + r;  // D row = node index
      uint4 v;
      v.x = pk[r][0]; v.y = pk[r][1]; v.z = pk[r][2]; v.w = pk[r][3];
      ((uint4*)Gp)[(size_t)(m * 2 + kq) * 64 + fcw * 16 + n16] = v;
    }
    __syncthreads();  // Gp ready; eh writes ordered before first phase-2 read
    // ---- phase 2: register-resident edge partials (hv from LDS broadcast) ----
    const uint4* ehb = (const uint4*)(eh + cc * EHW);
#pragma unroll
    for (int s = 0; s < ESLOT; ++s) {
      const int li = w + 8 * s;
      if (li < ecap) {
        const int2 sd = eStage[li];
        const int m = sd.x - n0;
        uint4 hv0 = ehb[li * 2], hv1 = ehb[li * 2 + 1];
        const uint4* gb = (const uint4*)Gp + (size_t)(m * 2) * 64 + lane;
        uint4 g0 = gb[0], g1 = gb[64];
        float p = acc[s];
        p = dot2a(g0.x, hv0.x, p);
        p = dot2a(g0.y, hv0.y, p);
        p = dot2a(g0.z, hv0.z, p);
        p = dot2a(g0.w, hv0.w, p);
        p = dot2a(g1.x, hv1.x, p);
        p = dot2a(g1.y, hv1.y, p);
        p = dot2a(g1.z, hv1.z, p);
        p = dot2a(g1.w, hv1.w, p);
        acc[s] = p;
      }
    }
    // overflow edges (virtually never): per-chunk atomic path, global hn1c
    for (int li = ECREG + w; li < ecnt; li += 8) {
      const int ii = e0 + li;
      const int src = __builtin_amdgcn_readfirstlane(esd[2 * ii]);
      const int dst = __builtin_amdgcn_readfirstlane(esd[2 * ii + 1]);
      const int m = src - n0;
      float p = (half == 0 && cc == 0) ? nbias[(size_t)src * 64 + lane] : 0.f;
      const uint4* hp = (const uint4*)(hn1c + ((size_t)c * EE + ii) * 8);
      uint4 hv0 = hp[0], hv1 = hp[1];
      const uint4* gb = (const uint4*)Gp + (size_t)(m * 2) * 64 + lane;
      uint4 g0 = gb[0], g1 = gb[64];
      p = dot2a(g0.x, hv0.x, p);
      p = dot2a(g0.y, hv0.y, p);
      p = dot2a(g0.z, hv0.z, p);
      p = dot2a(g0.w, hv0.w, p);
      p = dot2a(g1.x, hv1.x, p);
      p = dot2a(g1.y, hv1.y, p);
      p = dot2a(g1.z, hv1.z, p);
      p = dot2a(g1.w, hv1.w, p);
      atomicAdd(&aggr[(size_t)dst * 64 + lane], p);
    }
  }
  // ---- commit: one atomic per register-tracked edge ----
#pragma unroll
  for (int s = 0; s < ESLOT; ++s) {
    const int li = w + 8 * s;
    if (li < ecap) {
      const int dst = eStage[li].y;
      atomicAdd(&aggr[(size_t)dst * 64 + lane], acc[s]);
    }
  }
}

// ---------------- h update: 4 nodes/block; residual + aggr + root GEMM; re-zeros aggr ----------------
// Last layer (l==LL-1): hpk/nbias are dead -> skip their compute+writes.
__global__ __launch_bounds__(256) void k_update(
    float* __restrict__ h, uint_t* __restrict__ hpk,
    float* __restrict__ aggr, const float* __restrict__ bn2,
    const float* __restrict__ root, const float* __restrict__ cb,
    float* __restrict__ nbias, int l) {
  __shared__ float hl[4][DD];
  __shared__ float al[4][DD];
  const int tid = threadIdx.x, w = tid >> 6, f = tid & 63;
  const int n = blockIdx.x * 4 + w;
  float hv = h[(size_t)n * DD + f];
  hl[w][f] = hv;
  float acc = hv + aggr[(size_t)n * DD + f] + cb[l * DD + f];
  aggr[(size_t)n * DD + f] = 0.f;
  __syncthreads();
  const float* rp = root + (size_t)l * DD2;
#pragma unroll
  for (int d = 0; d < DD; ++d) acc += hl[w][d] * rp[d * DD + f];
  h[(size_t)n * DD + f] = acc;
  if (l == LL - 1) return;  // hpk/nbias dead after last conv layer
  al[w][f] = acc;
  float other = __shfl_down(acc, 1);
  if ((f & 1) == 0)
    hpk[(size_t)n * 32 + (f >> 1)] = pack2(acc, other);
  __syncthreads();
  float nb = 0.f;
#pragma unroll
  for (int d = 0; d < DD; ++d) nb += al[w][d] * bn2[d * DD + f];
  nbias[(size_t)n * DD + f] = nb;
}

// ---------------- fused Set2Set (3x LSTM+attention) + output MLP ----------------
// Wave-parallel attention (R8): wave w computes node base+w's dot with a
// coalesced 64-lane load + shuffle reduce; wave 0 does max/exp/sum.
#define EVCAP 2048
__global__ void k_s2s(const float* __restrict__ h, const int* __restrict__ goff,
                      const float* __restrict__ Wiht, const float* __restrict__ Whht,
                      const float* __restrict__ lb,
                      const float* __restrict__ Wo1, const float* __restrict__ bo1,
                      const float* __restrict__ Wo2, const float* __restrict__ bo2,
                      void* __restrict__ outv, const int* __restrict__ flag) {
  __shared__ float qsl[K1];
  __shared__ float hsl[DD];
  __shared__ float csl[DD];
  __shared__ float gl[4][DD];
  __shared__ float ev[EVCAP];
  __shared__ float rp4[4][DD];
  __shared__ float smax, ssum;
  const int g = blockIdx.x, tid = threadIdx.x;
  const int w = tid >> 6, lane = tid & 63;

  if (tid < K1) qsl[tid] = 0.f;
  else if (tid < K1 + DD) hsl[tid - K1] = 0.f;
  else csl[tid - K1 - DD] = 0.f;
  __syncthreads();

  const int i0 = goff[g];
  int cnt = goff[g + 1] - i0;
  if (cnt > EVCAP) cnt = EVCAP;

  for (int m = 0; m < MM; ++m) {
    {
      float a = lb[tid];
      for (int i = 0; i < K1; ++i) a += qsl[i] * Wiht[i * 256 + tid];
      for (int i = 0; i < DD; ++i) a += hsl[i] * Whht[i * 256 + tid];
      gl[tid >> 6][tid & 63] = a;
    }
    __syncthreads();
    if (tid < DD) {
      float ig = sigmf_(gl[0][tid]), fg = sigmf_(gl[1][tid]);
      float gg = tanhf(gl[2][tid]), og = sigmf_(gl[3][tid]);
      float c = fg * csl[tid] + ig * gg;
      csl[tid] = c;
      hsl[tid] = og * tanhf(c);
    }
    __syncthreads();
    const float qv = hsl[lane];
    for (int base = 0; base < cnt; base += 4) {
      const int j = base + w;
      float e = 0.f;
      if (j < cnt) e = h[(size_t)(i0 + j) * DD + lane] * qv;
#pragma unroll
      for (int off = 32; off > 0; off >>= 1) e += __shfl_down(e, off);
      if (lane == 0 && j < cnt) ev[j] = e;
    }
    __syncthreads();
    if (w == 0) {
      float lm = -1e30f;
      for (int jj = lane; jj < cnt; jj += 64) lm = fmaxf(lm, ev[jj]);
#pragma unroll
      for (int off = 32; off > 0; off >>= 1) lm = fmaxf(lm, __shfl_down(lm, off));
      const float emax = __shfl(lm, 0);
      float ls = 0.f;
      for (int jj = lane; jj < cnt; jj += 64) {
        float ex = expf(ev[jj] - emax);
        ev[jj] = ex;
        ls += ex;
      }
#pragma unroll
      for (int off = 32; off > 0; off >>= 1) ls += __shfl_down(ls, off);
      if (lane == 0) { smax = emax; ssum = ls; }
    }
    __syncthreads();
    const float denom = ssum;
    float racc = 0.f;
    for (int jj = w; jj < cnt; jj += 4)
      racc += ev[jj] * h[(size_t)(i0 + jj) * DD + lane];
    rp4[w][lane] = racc;
    __syncthreads();
    if (tid < DD) {
      float r = rp4[0][tid] + rp4[1][tid] + rp4[2][tid] + rp4[3][tid];
      r = (cnt > 0 && denom > 0.f) ? r / denom : 0.f;
      qsl[tid] = hsl[tid];
      qsl[DD + tid] = r;
    }
    __syncthreads();
  }
  if (tid < DD) {
    float t = bo1[tid];
    for (int i = 0; i < K1; ++i) t += qsl[i] * Wo1[i * DD + tid];
    float s = siluf_(t) * Wo2[tid];
    for (int off = 32; off > 0; off >>= 1) s += __shfl_down(s, off);
    if (tid == 0) {
      float v = s + bo2[0];
      if (*flag) ((ushort_t*)outv)[g] = f2bf(v);
      else       ((float*)outv)[g] = v;
    }
  }
}

extern "C" void kernel_launch(void* const* d_in, const int* in_sizes, int n_in,
                              void* d_out, int out_size, void* d_ws, size_t ws_size,
                              hipStream_t stream) {
  const void* x_r    = d_in[0];
  const int*  ei     = (const int*)d_in[1];
  const void* ea_r   = d_in[2];
  const int*  batch  = (const int*)d_in[3];
  const void* W0_r   = d_in[4];
  const void* b0_r   = d_in[5];
  const void* Wn1_r  = d_in[6];
  const void* bn1_r  = d_in[7];
  const void* Wn2_r  = d_in[8];
  const void* bn2_r  = d_in[9];
  const void* root_r = d_in[10];
  const void* cb_r   = d_in[11];
  const void* Wih_r  = d_in[12];
  const void* Whh_r  = d_in[13];
  const void* lb_r   = d_in[14];
  const void* Wo1_r  = d_in[15];
  const void* bo1_r  = d_in[16];
  const void* Wo2_r  = d_in[17];
  const void* bo2_r  = d_in[18];

  char* w = (char*)d_ws;
  size_t off = 0;
  auto alloc = [&](size_t bytes) -> void* {
    void* p = w + off;
    off = (off + bytes + 255) & ~(size_t)255;
    return p;
  };
  int* flag = (int*)alloc(4);
  float* xc    = (float*)alloc((size_t)NN * DIN_ * 4);
  float* eac   = (float*)alloc((size_t)EE * 4 * 4);
  float* W0c   = (float*)alloc((size_t)DIN_ * DD * 4);
  float* b0c   = (float*)alloc((size_t)DD * 4);
  float* Wn1c  = (float*)alloc((size_t)4 * K1 * 4);
  float* bn1c  = (float*)alloc((size_t)K1 * 4);
  float* bn2c  = (float*)alloc((size_t)DD2 * 4);
  float* rootc = (float*)alloc((size_t)LL * DD2 * 4);
  float* cbc   = (float*)alloc((size_t)LL * DD * 4);
  float* Wihc  = (float*)alloc((size_t)4 * DD * K1 * 4);
  float* Whhc  = (float*)alloc((size_t)4 * DD * DD * 4);
  float* lbc   = (float*)alloc((size_t)4 * DD * 4);
  float* Wo1c  = (float*)alloc((size_t)K1 * DD * 4);
  float* bo1c  = (float*)alloc((size_t)DD * 4);
  float* Wo2c  = (float*)alloc((size_t)DD * 4);
  float* bo2c  = (float*)alloc((size_t)4);
  float* Wiht  = (float*)alloc((size_t)K1 * 256 * 4);
  float* Whht  = (float*)alloc((size_t)DD * 256 * 4);
  uint_t* Wn2m = (uint_t*)alloc((size_t)64 * 4 * 2 * 2 * 64 * 4 * 4);  // 1 MB
  float*  h    = (float*)alloc((size_t)NN * DD * 4);
  uint_t* hpk  = (uint_t*)alloc((size_t)NN * 32 * 4);
  uint_t* hn1c = (uint_t*)alloc((size_t)EE * (K1 / 2) * 4);  // chunk-major
  float*  aggr = (float*)alloc((size_t)NN * DD * 4);
  float*  nbias= (float*)alloc((size_t)NN * DD * 4);
  int* cnts  = (int*)alloc((size_t)2 * NN * 4);
  int* rps   = (int*)alloc((size_t)(NN + 1) * 4);
  int* epos  = (int*)alloc((size_t)EE * 4);
  int* esd   = (int*)alloc((size_t)2 * EE * 4);
  int* goff  = (int*)alloc((size_t)(BB + 1) * 4);

  int* cnt_s = cnts;
  int* cur_s = cnts + NN;

  hipMemsetAsync(cnts, 0, (size_t)2 * NN * 4, stream);
  hipMemsetAsync(aggr, 0, (size_t)NN * DD * 4, stream);

  CanonArgs ca;
  const void* srcs[NCANON] = {x_r, ea_r, W0_r, b0_r, Wn1_r, bn1_r, bn2_r, root_r,
                              cb_r, Wih_r, Whh_r, lb_r, Wo1_r, bo1_r, Wo2_r, bo2_r};
  float* dsts[NCANON] = {xc, eac, W0c, b0c, Wn1c, bn1c, bn2c, rootc,
                         cbc, Wihc, Whhc, lbc, Wo1c, bo1c, Wo2c, bo2c};
  int cnts_c[NCANON] = {NN * DIN_, EE * 4, DIN_ * DD, DD, 4 * K1, K1, DD2, LL * DD2,
                        LL * DD, 4 * DD * K1, 4 * DD * DD, 4 * DD, K1 * DD, DD, DD, 1};
  for (int i = 0; i < NCANON; ++i) { ca.src[i] = srcs[i]; ca.dst[i] = dsts[i]; ca.n[i] = cnts_c[i]; }
  {
    dim3 grid((EE * 4 + 255) / 256, NCANON);
    k_canon<<<grid, 256, 0, stream>>>(ca, (const ushort_t*)ea_r, flag);
  }
  k_wn2m<<<K1, 256, 0, stream>>>(Wn2_r, Wn2m, flag);
  k_wT<<<(4 * DD * K1 + 255) / 256, 256, 0, stream>>>(Wihc, Whhc, Wiht, Whht);

  k_embed<<<NN / 4, 256, 0, stream>>>(xc, W0c, b0c, bn2c, h, hpk, nbias);
  k_hist<<<(EE + 255) / 256, 256, 0, stream>>>(ei, cnt_s);
  k_scan<<<2, 1024, 0, stream>>>(cnt_s, rps, batch, goff);
  k_fill<<<(EE + 255) / 256, 256, 0, stream>>>(ei, rps, cur_s, epos, esd);
  k_edgemlp<<<(EE * (K1 / 2) + 255) / 256, 256, 0, stream>>>(eac, Wn1c, bn1c, epos, hn1c);

  for (int l = 0; l < LL; ++l) {
    k_conv<<<CSPL * (NN / NPB), 512, 0, stream>>>(hpk, hn1c, Wn2m, nbias, rps, esd, aggr);
    k_update<<<NN / 4, 256, 0, stream>>>(h, hpk, aggr, bn2c, rootc, cbc, nbias, l);
  }

  k_s2s<<<BB, 256, 0, stream>>>(h, goff, Wiht, Whht, lbc, Wo1c, bo1c, Wo2c, bo2c,
                                d_out, flag);
}